// Round 1
// baseline (284.200 us; speedup 1.0000x reference)
//
#include <hip/hip_runtime.h>
#include <hip/hip_bf16.h>
#include <math.h>

#define NTOT  8192
#define DIM   512
#define BATCH (NTOT/2)
#define TEMP_INV 5.0f   // 1/0.2

typedef __attribute__((ext_vector_type(8))) short bf16x8;
typedef __attribute__((ext_vector_type(4))) float f32x4;

// ---------------- normalize: zn = z / max(||z||,1e-12), cast to bf16 ----------------
__global__ __launch_bounds__(256)
void normalize_k(const float* __restrict__ z, __hip_bfloat16* __restrict__ zn)
{
    const int row  = blockIdx.x;
    const int tid  = threadIdx.x;
    const int lane = tid & 63, wave = tid >> 6;
    const float* zr = z + (size_t)row * DIM;
    float v0 = zr[tid];
    float v1 = zr[tid + 256];
    float ss = v0 * v0 + v1 * v1;
    #pragma unroll
    for (int off = 32; off > 0; off >>= 1) ss += __shfl_down(ss, off);
    __shared__ float wpart[4];
    if (lane == 0) wpart[wave] = ss;
    __syncthreads();
    const float tot = wpart[0] + wpart[1] + wpart[2] + wpart[3];
    const float nrm = fmaxf(sqrtf(tot), 1e-12f);
    const float inv = 1.0f / nrm;
    __hip_bfloat16* zo = zn + (size_t)row * DIM;
    zo[tid]       = __float2bfloat16(v0 * inv);
    zo[tid + 256] = __float2bfloat16(v1 * inv);
}

// ---------------- sim pass: 128x128 tile, bf16 MFMA 16x16x32 ----------------
// PASS==0: accumulate per-column sum(sim), sum(sim^2)  -> rowsum/rowsumsq
// PASS==1: accumulate neg_sum = sum over (labels differ) of
//          exp(sim/T + (1-sim-mu[j])^2 * inv2s2[j])
template<int PASS>
__global__ __launch_bounds__(256, 2)
void sim_pass(const __hip_bfloat16* __restrict__ zn,
              const int*   __restrict__ labels,
              const float* __restrict__ mu_d,
              const float* __restrict__ inv2s2,
              float*  __restrict__ rowsum,
              float*  __restrict__ rowsumsq,
              double* __restrict__ neg_acc)
{
    constexpr int BM = 128, BN = 128, BK = 32;
    __shared__ unsigned short At[BM * BK];   // 8 KB, row-major [128][32], no pad (global_load_lds)
    __shared__ unsigned short Bt[BN * BK];   // 8 KB
    __shared__ float redbuf[4];

    const int tid  = threadIdx.x;
    const int wave = tid >> 6;
    const int lane = tid & 63;
    const int R0 = blockIdx.y * BM;
    const int C0 = blockIdx.x * BN;
    const int wr = wave >> 1, wc = wave & 1;   // 2x2 wave grid, 64x64 per wave

    f32x4 acc[4][4];
    #pragma unroll
    for (int r = 0; r < 4; ++r)
        #pragma unroll
        for (int c = 0; c < 4; ++c)
            acc[r][c] = (f32x4){0.f, 0.f, 0.f, 0.f};

    const int ldrow = lane >> 2;         // 0..15 within 16-row segment
    const int ldcol = (lane & 3) * 8;    // 0,8,16,24

    for (int k0 = 0; k0 < DIM; k0 += BK) {
        // stage A (rows R0..) and B (rows C0..): 8 x 1KB wave-loads each
        #pragma unroll
        for (int q = 0; q < 2; ++q) {
            const int s   = wave * 2 + q;        // segment 0..7 = 16 rows each
            const int row = s * 16 + ldrow;
            const __hip_bfloat16* ga = zn + (size_t)(R0 + row) * DIM + k0 + ldcol;
            const __hip_bfloat16* gb = zn + (size_t)(C0 + row) * DIM + k0 + ldcol;
            __builtin_amdgcn_global_load_lds(
                (const __attribute__((address_space(1))) unsigned int*)ga,
                (__attribute__((address_space(3))) unsigned int*)(At + s * 512 + lane * 8),
                16, 0, 0);
            __builtin_amdgcn_global_load_lds(
                (const __attribute__((address_space(1))) unsigned int*)gb,
                (__attribute__((address_space(3))) unsigned int*)(Bt + s * 512 + lane * 8),
                16, 0, 0);
        }
        __syncthreads();

        bf16x8 af[4], bfr[4];
        const int frow = lane & 15;
        const int fcol = (lane >> 4) * 8;    // k-offset of this quad
        #pragma unroll
        for (int r = 0; r < 4; ++r)
            af[r] = *(const bf16x8*)(At + (wr * 64 + r * 16 + frow) * BK + fcol);
        #pragma unroll
        for (int c = 0; c < 4; ++c)
            bfr[c] = *(const bf16x8*)(Bt + (wc * 64 + c * 16 + frow) * BK + fcol);

        #pragma unroll
        for (int r = 0; r < 4; ++r)
            #pragma unroll
            for (int c = 0; c < 4; ++c)
                acc[r][c] = __builtin_amdgcn_mfma_f32_16x16x32_bf16(af[r], bfr[c], acc[r][c], 0, 0, 0);
        __syncthreads();
    }

    // C/D layout per tile: col = lane&15, row = (lane>>4)*4 + t
    if (PASS == 0) {
        float* colsum   = (float*)At;        // 128 floats
        float* colsumsq = colsum + BN;       // 128 floats
        ((float*)At)[tid] = 0.f;             // zero all 256
        __syncthreads();
        #pragma unroll
        for (int c = 0; c < 4; ++c) {
            float s = 0.f, sq = 0.f;
            #pragma unroll
            for (int r = 0; r < 4; ++r) {
                const f32x4 v = acc[r][c];
                #pragma unroll
                for (int t = 0; t < 4; ++t) { s += v[t]; sq += v[t] * v[t]; }
            }
            const int jl = wc * 64 + c * 16 + (lane & 15);
            atomicAdd(&colsum[jl], s);
            atomicAdd(&colsumsq[jl], sq);
        }
        __syncthreads();
        if (tid < BN) {
            atomicAdd(&rowsum[C0 + tid],   colsum[tid]);
            atomicAdd(&rowsumsq[C0 + tid], colsumsq[tid]);
        }
    } else {
        float local = 0.f;
        int labj[4]; float muv[4], isv[4];
        #pragma unroll
        for (int c = 0; c < 4; ++c) {
            const int j = C0 + wc * 64 + c * 16 + (lane & 15);
            labj[c] = labels[j];
            muv[c]  = mu_d[j];
            isv[c]  = inv2s2[j];
        }
        #pragma unroll
        for (int r = 0; r < 4; ++r) {
            const int ib = R0 + wr * 64 + r * 16 + (lane >> 4) * 4;
            #pragma unroll
            for (int t = 0; t < 4; ++t) {
                const int li = labels[ib + t];
                #pragma unroll
                for (int c = 0; c < 4; ++c) {
                    if (li != labj[c]) {      // diagonal auto-excluded (label equals itself)
                        const float sim = acc[r][c][t];
                        const float dv  = (1.0f - sim) - muv[c];
                        local += __expf(sim * TEMP_INV + dv * dv * isv[c]);
                    }
                }
            }
        }
        #pragma unroll
        for (int off = 32; off > 0; off >>= 1) local += __shfl_down(local, off);
        if (lane == 0) redbuf[wave] = local;
        __syncthreads();
        if (tid == 0)
            atomicAdd(neg_acc, (double)(redbuf[0] + redbuf[1] + redbuf[2] + redbuf[3]));
    }
}

// ---------------- stats finalize: mu = 1 - mean(sim), inv2s2 = 1/(2*var_unbiased) ----------------
__global__ void finalize_stats_k(const float* __restrict__ rowsum,
                                 const float* __restrict__ rowsumsq,
                                 float* __restrict__ mu_d,
                                 float* __restrict__ inv2s2)
{
    const int j = blockIdx.x * blockDim.x + threadIdx.x;
    if (j < NTOT) {
        const float s  = rowsum[j];
        const float sq = rowsumsq[j];
        const float mean_sim = s * (1.0f / NTOT);
        // sum((dist-mu)^2) == sum((sim-mean_sim)^2) = sq - s*mean_sim ; ddof=1
        const float var = (sq - s * mean_sim) * (1.0f / (NTOT - 1));
        mu_d[j]   = 1.0f - mean_sim;
        inv2s2[j] = 1.0f / (2.0f * var);
    }
}

// ---------------- positive pairs ----------------
__global__ __launch_bounds__(256)
void pos_k(const __hip_bfloat16* __restrict__ zn, const int* __restrict__ labels,
           double* __restrict__ pos_acc)
{
    const int wave = threadIdx.x >> 6, lane = threadIdx.x & 63;
    const int pair = blockIdx.x * 4 + wave;
    const __hip_bfloat16* a = zn + (size_t)pair * DIM;
    const __hip_bfloat16* b = zn + (size_t)(pair + BATCH) * DIM;
    float s = 0.f;
    for (int k = lane; k < DIM; k += 64)
        s += __bfloat162float(a[k]) * __bfloat162float(b[k]);
    #pragma unroll
    for (int off = 32; off > 0; off >>= 1) s += __shfl_down(s, off);
    if (lane == 0 && labels[pair] == labels[pair + BATCH])
        atomicAdd(pos_acc, (double)__expf(s * TEMP_INV));
}

// ---------------- final loss ----------------
__global__ void loss_k(const double* __restrict__ accs, float* __restrict__ out)
{
    const double neg = accs[0], pos = accs[1];
    out[0] = (float)(-log(pos / (pos + neg)));
}

extern "C" void kernel_launch(void* const* d_in, const int* in_sizes, int n_in,
                              void* d_out, int out_size, void* d_ws, size_t ws_size,
                              hipStream_t stream)
{
    const float* z      = (const float*)d_in[0];
    const int*   labels = (const int*)d_in[1];
    float* out = (float*)d_out;

    char* ws = (char*)d_ws;
    __hip_bfloat16* zn = (__hip_bfloat16*)ws;
    const size_t ZN_BYTES = (size_t)NTOT * DIM * 2;        // 8 MiB
    float*  rowsum   = (float*)(ws + ZN_BYTES);
    float*  rowsumsq = rowsum + NTOT;
    float*  mu_d     = rowsum + 2 * NTOT;
    float*  inv2s2   = rowsum + 3 * NTOT;
    double* accs     = (double*)(rowsum + 4 * NTOT);       // [0]=neg, [1]=pos

    // zero rowsum/rowsumsq (+mu/inv2s2, harmless) and the two double accumulators
    hipMemsetAsync(rowsum, 0, 4 * NTOT * sizeof(float) + 2 * sizeof(double), stream);

    normalize_k<<<NTOT, 256, 0, stream>>>(z, zn);

    dim3 grid(NTOT / 128, NTOT / 128);
    sim_pass<0><<<grid, 256, 0, stream>>>(zn, labels, mu_d, inv2s2, rowsum, rowsumsq, accs);
    finalize_stats_k<<<NTOT / 256, 256, 0, stream>>>(rowsum, rowsumsq, mu_d, inv2s2);
    sim_pass<1><<<grid, 256, 0, stream>>>(zn, labels, mu_d, inv2s2, rowsum, rowsumsq, accs);
    pos_k<<<BATCH / 4, 256, 0, stream>>>(zn, labels, accs + 1);
    loss_k<<<1, 1, 0, stream>>>(accs, out);
}

// Round 2
// 247.466 us; speedup vs baseline: 1.1484x; 1.1484x over previous
//
#include <hip/hip_runtime.h>
#include <hip/hip_bf16.h>
#include <math.h>

#define NTOT  8192
#define DIM   512
#define BATCH (NTOT/2)
#define TEMP_INV 5.0f   // 1/0.2
#define TTILE 64                      // 8192 / 128 tiles per side
#define NBLK  (TTILE*(TTILE+1)/2)     // 2080 upper-triangle tiles

typedef __attribute__((ext_vector_type(8))) short bf16x8;
typedef __attribute__((ext_vector_type(4))) float f32x4;

__device__ __forceinline__ int tri_off(int x) { return x * (2 * TTILE + 1 - x) / 2; }

// ---------------- normalize: zn = z / max(||z||,1e-12), cast to bf16 ----------------
__global__ __launch_bounds__(256)
void normalize_k(const float* __restrict__ z, __hip_bfloat16* __restrict__ zn)
{
    const int row  = blockIdx.x;
    const int tid  = threadIdx.x;
    const int lane = tid & 63, wave = tid >> 6;
    const float2 v = ((const float2*)(z + (size_t)row * DIM))[tid];
    float ss = v.x * v.x + v.y * v.y;
    #pragma unroll
    for (int off = 32; off > 0; off >>= 1) ss += __shfl_down(ss, off);
    __shared__ float wpart[4];
    if (lane == 0) wpart[wave] = ss;
    __syncthreads();
    const float tot = wpart[0] + wpart[1] + wpart[2] + wpart[3];
    const float inv = 1.0f / fmaxf(sqrtf(tot), 1e-12f);
    __hip_bfloat162* zo = (__hip_bfloat162*)(zn + (size_t)row * DIM);
    zo[tid] = __halves2bfloat162(__float2bfloat16(v.x * inv), __float2bfloat16(v.y * inv));
}

// ---------------- symmetric sim pass: 128x128 tiles, upper triangle only ----------------
// LDS layout: 16 segments/side of 1KB; segment (rowseg, khalf) slot l holds
// global (row rowseg*16 + (l&15), k = k0 + khalf*32 + (l>>4)*8) -- exact MFMA
// A-frag order, so fragment reads are seg_base + lane*16 (conflict-free).
template<int PASS>
__global__ __launch_bounds__(256, 4)
void sim_pass(const __hip_bfloat16* __restrict__ zn,
              const int*   __restrict__ labels,
              const float* __restrict__ mu_d,
              const float* __restrict__ inv2s2,
              float*  __restrict__ rowsum,
              float*  __restrict__ rowsumsq,
              double* __restrict__ neg_acc)
{
    __shared__ unsigned short Asm[8192];   // 16 KB = 16 segs (8 rowsegs x 2 khalf)
    __shared__ unsigned short Bsm[8192];   // 16 KB
    __shared__ float redbuf[4];

    const int tid  = threadIdx.x;
    const int wave = tid >> 6;
    const int lane = tid & 63;
    const int f_l  = lane & 15;       // fragment row within 16
    const int q_l  = lane >> 4;       // fragment k-quad

    // decode upper-triangle tile index -> (bi, bj), bi <= bj
    const int t = blockIdx.x;
    int bi = (int)(0.5f * (129.0f - sqrtf(16641.0f - 8.0f * (float)t)));
    if (bi > TTILE - 1) bi = TTILE - 1;
    if (bi < 0) bi = 0;
    while (tri_off(bi + 1) <= t) ++bi;
    while (tri_off(bi)     >  t) --bi;
    const int bj = bi + (t - tri_off(bi));
    const int R0 = bi * 128, C0 = bj * 128;
    const int wr = wave >> 1, wc = wave & 1;    // 2x2 wave grid, 64x64 each

    f32x4 acc[4][4];
    #pragma unroll
    for (int r = 0; r < 4; ++r)
        #pragma unroll
        for (int c = 0; c < 4; ++c)
            acc[r][c] = (f32x4){0.f, 0.f, 0.f, 0.f};

    for (int k0 = 0; k0 < DIM; k0 += 64) {
        #pragma unroll
        for (int s = 0; s < 4; ++s) {
            const int seg    = wave * 4 + s;     // 0..15
            const int rowseg = seg >> 1;
            const int kh     = seg & 1;
            const int gk     = k0 + kh * 32 + q_l * 8;
            const __hip_bfloat16* ga = zn + (size_t)(R0 + rowseg * 16 + f_l) * DIM + gk;
            const __hip_bfloat16* gb = zn + (size_t)(C0 + rowseg * 16 + f_l) * DIM + gk;
            __builtin_amdgcn_global_load_lds(
                (const __attribute__((address_space(1))) unsigned int*)ga,
                (__attribute__((address_space(3))) unsigned int*)(Asm + seg * 512 + lane * 8),
                16, 0, 0);
            __builtin_amdgcn_global_load_lds(
                (const __attribute__((address_space(1))) unsigned int*)gb,
                (__attribute__((address_space(3))) unsigned int*)(Bsm + seg * 512 + lane * 8),
                16, 0, 0);
        }
        __syncthreads();

        #pragma unroll
        for (int h = 0; h < 2; ++h) {
            bf16x8 af[4], bfr[4];
            #pragma unroll
            for (int r = 0; r < 4; ++r)
                af[r] = *(const bf16x8*)(Asm + ((wr * 4 + r) * 2 + h) * 512 + lane * 8);
            #pragma unroll
            for (int c = 0; c < 4; ++c)
                bfr[c] = *(const bf16x8*)(Bsm + ((wc * 4 + c) * 2 + h) * 512 + lane * 8);
            #pragma unroll
            for (int r = 0; r < 4; ++r)
                #pragma unroll
                for (int c = 0; c < 4; ++c)
                    acc[r][c] = __builtin_amdgcn_mfma_f32_16x16x32_bf16(af[r], bfr[c], acc[r][c], 0, 0, 0);
        }
        __syncthreads();
    }

    // C/D layout: col = f_l (within 16), row = q_l*4 + u
    if (PASS == 0) {
        float* cs = (float*)Asm;          // col sums   (C-side), 128
        float* cq = cs + 128;             // col sumsq
        float* rs = cs + 256;             // row sums   (mirror to R-side)
        float* rq = cs + 384;
        cs[tid] = 0.f; cs[tid + 256] = 0.f;
        __syncthreads();
        #pragma unroll
        for (int c = 0; c < 4; ++c) {
            float s = 0.f, sq = 0.f;
            #pragma unroll
            for (int r = 0; r < 4; ++r) {
                const f32x4 v = acc[r][c];
                #pragma unroll
                for (int u = 0; u < 4; ++u) { s += v[u]; sq += v[u] * v[u]; }
            }
            atomicAdd(&cs[wc * 64 + c * 16 + f_l], s);
            atomicAdd(&cq[wc * 64 + c * 16 + f_l], sq);
        }
        if (bi != bj) {
            #pragma unroll
            for (int r = 0; r < 4; ++r) {
                float s0 = 0, s1 = 0, s2 = 0, s3 = 0, q0 = 0, q1 = 0, q2 = 0, q3 = 0;
                #pragma unroll
                for (int c = 0; c < 4; ++c) {
                    const f32x4 v = acc[r][c];
                    s0 += v[0]; s1 += v[1]; s2 += v[2]; s3 += v[3];
                    q0 += v[0] * v[0]; q1 += v[1] * v[1]; q2 += v[2] * v[2]; q3 += v[3] * v[3];
                }
                #pragma unroll
                for (int off = 1; off < 16; off <<= 1) {
                    s0 += __shfl_xor(s0, off); s1 += __shfl_xor(s1, off);
                    s2 += __shfl_xor(s2, off); s3 += __shfl_xor(s3, off);
                    q0 += __shfl_xor(q0, off); q1 += __shfl_xor(q1, off);
                    q2 += __shfl_xor(q2, off); q3 += __shfl_xor(q3, off);
                }
                if (f_l == 0) {
                    const int base = wr * 64 + r * 16 + q_l * 4;
                    atomicAdd(&rs[base + 0], s0); atomicAdd(&rs[base + 1], s1);
                    atomicAdd(&rs[base + 2], s2); atomicAdd(&rs[base + 3], s3);
                    atomicAdd(&rq[base + 0], q0); atomicAdd(&rq[base + 1], q1);
                    atomicAdd(&rq[base + 2], q2); atomicAdd(&rq[base + 3], q3);
                }
            }
        }
        __syncthreads();
        if (tid < 128) {
            atomicAdd(&rowsum[C0 + tid],   cs[tid]);
            atomicAdd(&rowsumsq[C0 + tid], cq[tid]);
            if (bi != bj) {
                atomicAdd(&rowsum[R0 + tid],   rs[tid]);
                atomicAdd(&rowsumsq[R0 + tid], rq[tid]);
            }
        }
    } else {
        int labj[4]; float muj[4], isj[4];
        #pragma unroll
        for (int c = 0; c < 4; ++c) {
            const int j = C0 + wc * 64 + c * 16 + f_l;
            labj[c] = labels[j];
            muj[c]  = mu_d[j];
            isj[c]  = inv2s2[j];
        }
        float local = 0.f;
        #pragma unroll
        for (int r = 0; r < 4; ++r) {
            const int ib = R0 + wr * 64 + r * 16 + q_l * 4;
            #pragma unroll
            for (int u = 0; u < 4; ++u) {
                const int   li = labels[ib + u];
                const float mi = mu_d[ib + u];
                const float vi = inv2s2[ib + u];
                #pragma unroll
                for (int c = 0; c < 4; ++c) {
                    const float s  = acc[r][c][u];
                    const float dj = (1.0f - s) - muj[c];
                    float e = __expf(s * TEMP_INV + dj * dj * isj[c]);
                    if (bi != bj) {                      // wave-uniform branch
                        const float di = (1.0f - s) - mi;
                        e += __expf(s * TEMP_INV + di * di * vi);
                    }
                    local += (li != labj[c]) ? e : 0.f;
                }
            }
        }
        #pragma unroll
        for (int off = 1; off < 64; off <<= 1) local += __shfl_xor(local, off);
        if (lane == 0) redbuf[wave] = local;
        __syncthreads();
        if (tid == 0)
            atomicAdd(neg_acc, (double)(redbuf[0] + redbuf[1] + redbuf[2] + redbuf[3]));
    }
}

// ---------------- stats finalize ----------------
__global__ void finalize_stats_k(const float* __restrict__ rowsum,
                                 const float* __restrict__ rowsumsq,
                                 float* __restrict__ mu_d,
                                 float* __restrict__ inv2s2)
{
    const int j = blockIdx.x * blockDim.x + threadIdx.x;
    if (j < NTOT) {
        const float s  = rowsum[j];
        const float sq = rowsumsq[j];
        const float mean_sim = s * (1.0f / NTOT);
        const float var = (sq - s * mean_sim) * (1.0f / (NTOT - 1));
        mu_d[j]   = 1.0f - mean_sim;
        inv2s2[j] = 1.0f / (2.0f * var);
    }
}

// ---------------- positive pairs ----------------
__global__ __launch_bounds__(256)
void pos_k(const __hip_bfloat16* __restrict__ zn, const int* __restrict__ labels,
           double* __restrict__ pos_acc)
{
    const int wave = threadIdx.x >> 6, lane = threadIdx.x & 63;
    const int pair = blockIdx.x * 4 + wave;
    const __hip_bfloat16* a = zn + (size_t)pair * DIM;
    const __hip_bfloat16* b = zn + (size_t)(pair + BATCH) * DIM;
    float s = 0.f;
    for (int k = lane; k < DIM; k += 64)
        s += __bfloat162float(a[k]) * __bfloat162float(b[k]);
    #pragma unroll
    for (int off = 32; off > 0; off >>= 1) s += __shfl_down(s, off);
    if (lane == 0 && labels[pair] == labels[pair + BATCH])
        atomicAdd(pos_acc, (double)__expf(s * TEMP_INV));
}

// ---------------- final loss ----------------
__global__ void loss_k(const double* __restrict__ accs, float* __restrict__ out)
{
    const double neg = accs[0], pos = accs[1];
    out[0] = (float)(-log(pos / (pos + neg)));
}

extern "C" void kernel_launch(void* const* d_in, const int* in_sizes, int n_in,
                              void* d_out, int out_size, void* d_ws, size_t ws_size,
                              hipStream_t stream)
{
    const float* z      = (const float*)d_in[0];
    const int*   labels = (const int*)d_in[1];
    float* out = (float*)d_out;

    char* ws = (char*)d_ws;
    __hip_bfloat16* zn = (__hip_bfloat16*)ws;
    const size_t ZN_BYTES = (size_t)NTOT * DIM * 2;        // 8 MiB
    float*  rowsum   = (float*)(ws + ZN_BYTES);
    float*  rowsumsq = rowsum + NTOT;
    float*  mu_d     = rowsum + 2 * NTOT;
    float*  inv2s2   = rowsum + 3 * NTOT;
    double* accs     = (double*)(rowsum + 4 * NTOT);       // [0]=neg, [1]=pos

    hipMemsetAsync(rowsum, 0, 4 * NTOT * sizeof(float) + 2 * sizeof(double), stream);

    normalize_k<<<NTOT, 256, 0, stream>>>(z, zn);

    sim_pass<0><<<NBLK, 256, 0, stream>>>(zn, labels, mu_d, inv2s2, rowsum, rowsumsq, accs);
    finalize_stats_k<<<NTOT / 256, 256, 0, stream>>>(rowsum, rowsumsq, mu_d, inv2s2);
    sim_pass<1><<<NBLK, 256, 0, stream>>>(zn, labels, mu_d, inv2s2, rowsum, rowsumsq, accs);
    pos_k<<<BATCH / 4, 256, 0, stream>>>(zn, labels, accs + 1);
    loss_k<<<1, 1, 0, stream>>>(accs, out);
}

// Round 3
// 230.794 us; speedup vs baseline: 1.2314x; 1.0722x over previous
//
#include <hip/hip_runtime.h>
#include <hip/hip_bf16.h>
#include <hip/hip_fp16.h>
#include <math.h>

#define NTOT  8192
#define DIM   512
#define BATCH (NTOT/2)
#define TEMP_INV 5.0f   // 1/0.2
#define TTILE 64                      // 8192 / 128 tiles per side
#define NBLK  (TTILE*(TTILE+1)/2)     // 2080 upper-triangle tiles
#define SIM_ELEMS ((size_t)NBLK * 16384)

typedef __attribute__((ext_vector_type(8))) short bf16x8;
typedef __attribute__((ext_vector_type(4))) float f32x4;

// column-major triangle decode: t = bj*(bj+1)/2 + bi, bi <= bj.
// consecutive t share bj (B-panel) and sweep bi prefix (A-panels) -> L2 reuse.
__device__ __forceinline__ void decode_tile(int t, int& bi, int& bj)
{
    int b = (int)((sqrtf(8.0f * (float)t + 1.0f) - 1.0f) * 0.5f);
    while ((b + 1) * (b + 2) / 2 <= t) ++b;
    while (b * (b + 1) / 2 > t)       --b;
    bj = b;
    bi = t - b * (b + 1) / 2;
}

__device__ __forceinline__ unsigned int pack_bf16_2(float a, float b)
{
    __hip_bfloat16 ha = __float2bfloat16(a), hb = __float2bfloat16(b);
    unsigned short ua, ub;
    __builtin_memcpy(&ua, &ha, 2); __builtin_memcpy(&ub, &hb, 2);
    return (unsigned int)ua | ((unsigned int)ub << 16);
}

// ---------------- normalize: one wave per row ----------------
__global__ __launch_bounds__(256)
void normalize_k(const float* __restrict__ z, __hip_bfloat16* __restrict__ zn)
{
    const int lane = threadIdx.x & 63, wave = threadIdx.x >> 6;
    const int row  = blockIdx.x * 4 + wave;
    const float4* zr = (const float4*)(z + (size_t)row * DIM);
    const float4 a = zr[lane];
    const float4 b = zr[lane + 64];
    float ss = a.x*a.x + a.y*a.y + a.z*a.z + a.w*a.w
             + b.x*b.x + b.y*b.y + b.z*b.z + b.w*b.w;
    #pragma unroll
    for (int off = 1; off < 64; off <<= 1) ss += __shfl_xor(ss, off);
    const float inv = 1.0f / fmaxf(sqrtf(ss), 1e-12f);
    uint2* zo = (uint2*)(zn + (size_t)row * DIM);
    uint2 o0, o1;
    o0.x = pack_bf16_2(a.x * inv, a.y * inv);
    o0.y = pack_bf16_2(a.z * inv, a.w * inv);
    o1.x = pack_bf16_2(b.x * inv, b.y * inv);
    o1.y = pack_bf16_2(b.z * inv, b.w * inv);
    zo[lane]      = o0;
    zo[lane + 64] = o1;
}

// ---------------- sim pass: 128x128 upper-tri tiles, dbuf prefetch K-loop ----------------
// LDS layout per buffer: 16 segs of 1KB in exact MFMA A-frag order:
// seg (rowseg, khalf), slot l = (row rowseg*16+(l&15), k khalf*32+(l>>4)*8).
// Fragment reads are seg_base + lane*16B (conflict-free, matches global_load_lds pattern).
template<int PASS, bool STORE>
__global__ __launch_bounds__(256, 2)
void sim_pass(const __hip_bfloat16* __restrict__ zn,
              const int*   __restrict__ labels,
              const float* __restrict__ mu_d,
              const float* __restrict__ inv2s2,
              float*  __restrict__ rowsum,
              float*  __restrict__ rowsumsq,
              double* __restrict__ neg_acc,
              __half* __restrict__ simout)
{
    __shared__ unsigned short Asm[2][8192];   // 2 x 16 KB
    __shared__ unsigned short Bsm[2][8192];
    __shared__ float redbuf[4];

    const int tid  = threadIdx.x;
    const int wave = tid >> 6;
    const int lane = tid & 63;
    const int f_l  = lane & 15;
    const int q_l  = lane >> 4;

    int bi, bj;
    decode_tile(blockIdx.x, bi, bj);
    const int R0 = bi * 128, C0 = bj * 128;
    const int wr = wave >> 1, wc = wave & 1;

    auto issue = [&](int k0, int buf) {
        #pragma unroll
        for (int s = 0; s < 4; ++s) {
            const int seg    = wave * 4 + s;
            const int rowseg = seg >> 1;
            const int kh     = seg & 1;
            const int gk     = k0 + kh * 32 + q_l * 8;
            const __hip_bfloat16* ga = zn + (size_t)(R0 + rowseg * 16 + f_l) * DIM + gk;
            const __hip_bfloat16* gb = zn + (size_t)(C0 + rowseg * 16 + f_l) * DIM + gk;
            __builtin_amdgcn_global_load_lds(
                (const __attribute__((address_space(1))) unsigned int*)ga,
                (__attribute__((address_space(3))) unsigned int*)(&Asm[buf][0] + seg * 512 + lane * 8),
                16, 0, 0);
            __builtin_amdgcn_global_load_lds(
                (const __attribute__((address_space(1))) unsigned int*)gb,
                (__attribute__((address_space(3))) unsigned int*)(&Bsm[buf][0] + seg * 512 + lane * 8),
                16, 0, 0);
        }
    };

    f32x4 acc[4][4];
    #pragma unroll
    for (int r = 0; r < 4; ++r)
        #pragma unroll
        for (int c = 0; c < 4; ++c)
            acc[r][c] = (f32x4){0.f, 0.f, 0.f, 0.f};

    issue(0, 0);

    for (int ki = 0; ki < 8; ++ki) {
        __syncthreads();   // drains this wave's loads(ki) (vmcnt) + prev iter's ds_reads (lgkm)
        const unsigned short* Ab = &Asm[ki & 1][0];
        const unsigned short* Bb = &Bsm[ki & 1][0];
        bf16x8 af[4][2], bfr[4][2];
        #pragma unroll
        for (int r = 0; r < 4; ++r)
            #pragma unroll
            for (int h = 0; h < 2; ++h)
                af[r][h] = *(const bf16x8*)(Ab + ((wr * 4 + r) * 2 + h) * 512 + lane * 8);
        #pragma unroll
        for (int c = 0; c < 4; ++c)
            #pragma unroll
            for (int h = 0; h < 2; ++h)
                bfr[c][h] = *(const bf16x8*)(Bb + ((wc * 4 + c) * 2 + h) * 512 + lane * 8);
        if (ki < 7) issue((ki + 1) * 64, (ki + 1) & 1);   // prefetch into alt buffer
        #pragma unroll
        for (int h = 0; h < 2; ++h)
            #pragma unroll
            for (int r = 0; r < 4; ++r)
                #pragma unroll
                for (int c = 0; c < 4; ++c)
                    acc[r][c] = __builtin_amdgcn_mfma_f32_16x16x32_bf16(af[r][h], bfr[c][h], acc[r][c], 0, 0, 0);
    }
    __syncthreads();   // before reusing Asm as scratch / exiting

    // C/D layout: col = f_l, row = q_l*4 + u
    if (STORE) {
        // fragment-order store: tile t, elem = wave*4096 + (r*4+c)*256 + lane*4 + u
        __half* base = simout + (size_t)blockIdx.x * 16384 + wave * 4096;
        #pragma unroll
        for (int r = 0; r < 4; ++r)
            #pragma unroll
            for (int c = 0; c < 4; ++c) {
                const f32x4 v = acc[r][c];
                unsigned long long p =
                      (unsigned long long)__half_as_ushort(__float2half(v[0]))
                    | ((unsigned long long)__half_as_ushort(__float2half(v[1])) << 16)
                    | ((unsigned long long)__half_as_ushort(__float2half(v[2])) << 32)
                    | ((unsigned long long)__half_as_ushort(__float2half(v[3])) << 48);
                __builtin_nontemporal_store(p,
                    (unsigned long long*)(base + (r * 4 + c) * 256 + lane * 4));
            }
    }

    if (PASS == 0) {
        float* cs = (float*)&Asm[0][0];   // col sums (C-side), 128
        float* cq = cs + 128;
        float* rs = cs + 256;             // row sums (mirror, R-side)
        float* rq = cs + 384;
        cs[tid] = 0.f; cs[tid + 256] = 0.f;
        __syncthreads();
        #pragma unroll
        for (int c = 0; c < 4; ++c) {
            float s = 0.f, sq = 0.f;
            #pragma unroll
            for (int r = 0; r < 4; ++r) {
                const f32x4 v = acc[r][c];
                #pragma unroll
                for (int u = 0; u < 4; ++u) { s += v[u]; sq += v[u] * v[u]; }
            }
            atomicAdd(&cs[wc * 64 + c * 16 + f_l], s);
            atomicAdd(&cq[wc * 64 + c * 16 + f_l], sq);
        }
        if (bi != bj) {
            #pragma unroll
            for (int r = 0; r < 4; ++r) {
                float s0 = 0, s1 = 0, s2 = 0, s3 = 0, q0 = 0, q1 = 0, q2 = 0, q3 = 0;
                #pragma unroll
                for (int c = 0; c < 4; ++c) {
                    const f32x4 v = acc[r][c];
                    s0 += v[0]; s1 += v[1]; s2 += v[2]; s3 += v[3];
                    q0 += v[0] * v[0]; q1 += v[1] * v[1]; q2 += v[2] * v[2]; q3 += v[3] * v[3];
                }
                #pragma unroll
                for (int off = 1; off < 16; off <<= 1) {
                    s0 += __shfl_xor(s0, off); s1 += __shfl_xor(s1, off);
                    s2 += __shfl_xor(s2, off); s3 += __shfl_xor(s3, off);
                    q0 += __shfl_xor(q0, off); q1 += __shfl_xor(q1, off);
                    q2 += __shfl_xor(q2, off); q3 += __shfl_xor(q3, off);
                }
                if (f_l == 0) {
                    const int base = wr * 64 + r * 16 + q_l * 4;
                    atomicAdd(&rs[base + 0], s0); atomicAdd(&rs[base + 1], s1);
                    atomicAdd(&rs[base + 2], s2); atomicAdd(&rs[base + 3], s3);
                    atomicAdd(&rq[base + 0], q0); atomicAdd(&rq[base + 1], q1);
                    atomicAdd(&rq[base + 2], q2); atomicAdd(&rq[base + 3], q3);
                }
            }
        }
        __syncthreads();
        if (tid < 128) {
            atomicAdd(&rowsum[C0 + tid],   cs[tid]);
            atomicAdd(&rowsumsq[C0 + tid], cq[tid]);
            if (bi != bj) {
                atomicAdd(&rowsum[R0 + tid],   rs[tid]);
                atomicAdd(&rowsumsq[R0 + tid], rq[tid]);
            }
        }
    } else {
        // fallback recompute pass-1 (only used when ws too small for simout)
        int labj[4]; float muj[4], isj[4];
        #pragma unroll
        for (int c = 0; c < 4; ++c) {
            const int j = C0 + wc * 64 + c * 16 + f_l;
            labj[c] = labels[j]; muj[c] = mu_d[j]; isj[c] = inv2s2[j];
        }
        float local = 0.f;
        #pragma unroll
        for (int r = 0; r < 4; ++r) {
            const int ib = R0 + wr * 64 + r * 16 + q_l * 4;
            #pragma unroll
            for (int u = 0; u < 4; ++u) {
                const int   li = labels[ib + u];
                const float mi = mu_d[ib + u];
                const float vi = inv2s2[ib + u];
                #pragma unroll
                for (int c = 0; c < 4; ++c) {
                    const float s  = acc[r][c][u];
                    const float dj = (1.0f - s) - muj[c];
                    float e = __expf(s * TEMP_INV + dj * dj * isj[c]);
                    if (bi != bj) {
                        const float di = (1.0f - s) - mi;
                        e += __expf(s * TEMP_INV + di * di * vi);
                    }
                    local += (li != labj[c]) ? e : 0.f;
                }
            }
        }
        #pragma unroll
        for (int off = 1; off < 64; off <<= 1) local += __shfl_xor(local, off);
        if (lane == 0) redbuf[wave] = local;
        __syncthreads();
        if (tid == 0)
            atomicAdd(neg_acc, (double)(redbuf[0] + redbuf[1] + redbuf[2] + redbuf[3]));
    }
}

// ---------------- streaming neg-sum from stored sim ----------------
__global__ __launch_bounds__(256)
void neg_stream_k(const __half* __restrict__ sim,
                  const int*   __restrict__ labels,
                  const float* __restrict__ mu_d,
                  const float* __restrict__ inv2s2,
                  double* __restrict__ neg_acc)
{
    __shared__ int   labI[128], labJ[128];
    __shared__ float muI[128], muJ[128], isI[128], isJ[128];
    __shared__ float redbuf[4];
    const int tid = threadIdx.x;
    int bi, bj;
    decode_tile(blockIdx.x, bi, bj);
    const int R0 = bi * 128, C0 = bj * 128;
    if (tid < 128) {
        labI[tid] = labels[R0 + tid]; muI[tid] = mu_d[R0 + tid]; isI[tid] = inv2s2[R0 + tid];
    } else {
        const int j = tid - 128;
        labJ[j] = labels[C0 + j]; muJ[j] = mu_d[C0 + j]; isJ[j] = inv2s2[C0 + j];
    }
    __syncthreads();
    const bool diag = (bi == bj);
    const unsigned long long* base =
        (const unsigned long long*)(sim + (size_t)blockIdx.x * 16384);
    float local = 0.f;
    #pragma unroll 4
    for (int it = 0; it < 16; ++it) {
        const int qd = it * 256 + tid;         // quad index 0..4095
        const unsigned long long v = __builtin_nontemporal_load(base + qd);
        const int wv = qd >> 10, rc = (qd >> 6) & 15, ln = qd & 63;
        const int wr = wv >> 1, wc = wv & 1, r = rc >> 2, c = rc & 3;
        const int f = ln & 15, q = ln >> 4;
        const int irow = wr * 64 + r * 16 + q * 4;
        const int jcol = wc * 64 + c * 16 + f;
        const int   lj = labJ[jcol];
        const float mj = muJ[jcol], sj = isJ[jcol];
        #pragma unroll
        for (int u = 0; u < 4; ++u) {
            const float s = __half2float(__ushort_as_half((unsigned short)(v >> (16 * u))));
            if (labI[irow + u] != lj) {
                const float d  = 1.0f - s;
                const float dj = d - mj;
                float e = __expf(s * TEMP_INV + dj * dj * sj);
                if (!diag) {
                    const float di = d - muI[irow + u];
                    e += __expf(s * TEMP_INV + di * di * isI[irow + u]);
                }
                local += e;
            }
        }
    }
    #pragma unroll
    for (int off = 1; off < 64; off <<= 1) local += __shfl_xor(local, off);
    if ((tid & 63) == 0) redbuf[tid >> 6] = local;
    __syncthreads();
    if (tid == 0)
        atomicAdd(neg_acc, (double)(redbuf[0] + redbuf[1] + redbuf[2] + redbuf[3]));
}

// ---------------- stats finalize ----------------
__global__ void finalize_stats_k(const float* __restrict__ rowsum,
                                 const float* __restrict__ rowsumsq,
                                 float* __restrict__ mu_d,
                                 float* __restrict__ inv2s2)
{
    const int j = blockIdx.x * blockDim.x + threadIdx.x;
    if (j < NTOT) {
        const float s  = rowsum[j];
        const float sq = rowsumsq[j];
        const float mean_sim = s * (1.0f / NTOT);
        const float var = (sq - s * mean_sim) * (1.0f / (NTOT - 1));
        mu_d[j]   = 1.0f - mean_sim;
        inv2s2[j] = 1.0f / (2.0f * var);
    }
}

// ---------------- positive pairs ----------------
__global__ __launch_bounds__(256)
void pos_k(const __hip_bfloat16* __restrict__ zn, const int* __restrict__ labels,
           double* __restrict__ pos_acc)
{
    const int wave = threadIdx.x >> 6, lane = threadIdx.x & 63;
    const int pair = blockIdx.x * 4 + wave;
    const __hip_bfloat16* a = zn + (size_t)pair * DIM;
    const __hip_bfloat16* b = zn + (size_t)(pair + BATCH) * DIM;
    float s = 0.f;
    for (int k = lane; k < DIM; k += 64)
        s += __bfloat162float(a[k]) * __bfloat162float(b[k]);
    #pragma unroll
    for (int off = 32; off > 0; off >>= 1) s += __shfl_down(s, off);
    if (lane == 0 && labels[pair] == labels[pair + BATCH])
        atomicAdd(pos_acc, (double)__expf(s * TEMP_INV));
}

// ---------------- final loss ----------------
__global__ void loss_k(const double* __restrict__ accs, float* __restrict__ out)
{
    const double neg = accs[0], pos = accs[1];
    out[0] = (float)(-log(pos / (pos + neg)));
}

extern "C" void kernel_launch(void* const* d_in, const int* in_sizes, int n_in,
                              void* d_out, int out_size, void* d_ws, size_t ws_size,
                              hipStream_t stream)
{
    const float* z      = (const float*)d_in[0];
    const int*   labels = (const int*)d_in[1];
    float* out = (float*)d_out;

    char* ws = (char*)d_ws;
    __hip_bfloat16* zn = (__hip_bfloat16*)ws;
    const size_t ZN_BYTES = (size_t)NTOT * DIM * 2;        // 8 MiB
    float*  rowsum   = (float*)(ws + ZN_BYTES);
    float*  rowsumsq = rowsum + NTOT;
    float*  mu_d     = rowsum + 2 * NTOT;
    float*  inv2s2   = rowsum + 3 * NTOT;
    double* accs     = (double*)(rowsum + 4 * NTOT);       // [0]=neg, [1]=pos
    const size_t simoff = (ZN_BYTES + 4 * NTOT * sizeof(float) + 2 * sizeof(double) + 255) & ~(size_t)255;
    __half* simbuf = (__half*)(ws + simoff);
    const bool store = ws_size >= simoff + SIM_ELEMS * sizeof(__half);

    hipMemsetAsync(rowsum, 0, 4 * NTOT * sizeof(float) + 2 * sizeof(double), stream);

    normalize_k<<<NTOT / 4, 256, 0, stream>>>(z, zn);

    if (store) {
        sim_pass<0, true><<<NBLK, 256, 0, stream>>>(zn, labels, mu_d, inv2s2,
                                                    rowsum, rowsumsq, accs, simbuf);
        finalize_stats_k<<<NTOT / 256, 256, 0, stream>>>(rowsum, rowsumsq, mu_d, inv2s2);
        neg_stream_k<<<NBLK, 256, 0, stream>>>(simbuf, labels, mu_d, inv2s2, accs);
    } else {
        sim_pass<0, false><<<NBLK, 256, 0, stream>>>(zn, labels, mu_d, inv2s2,
                                                     rowsum, rowsumsq, accs, nullptr);
        finalize_stats_k<<<NTOT / 256, 256, 0, stream>>>(rowsum, rowsumsq, mu_d, inv2s2);
        sim_pass<1, false><<<NBLK, 256, 0, stream>>>(zn, labels, mu_d, inv2s2,
                                                     rowsum, rowsumsq, accs, nullptr);
    }
    pos_k<<<BATCH / 4, 256, 0, stream>>>(zn, labels, accs + 1);
    loss_k<<<1, 1, 0, stream>>>(accs, out);
}

// Round 4
// 218.237 us; speedup vs baseline: 1.3023x; 1.0575x over previous
//
#include <hip/hip_runtime.h>
#include <hip/hip_bf16.h>
#include <hip/hip_fp16.h>
#include <math.h>

#define NTOT  8192
#define DIM   512
#define BATCH (NTOT/2)
#define TEMP_INV 5.0f   // 1/0.2
#define TTILE 64                      // 8192 / 128 tiles per side
#define NBLK  (TTILE*(TTILE+1)/2)     // 2080 upper-triangle tiles
#define SIM_ELEMS ((size_t)NBLK * 16384)

typedef __attribute__((ext_vector_type(8))) short bf16x8;
typedef __attribute__((ext_vector_type(4))) float f32x4;

// column-major triangle decode: t = bj*(bj+1)/2 + bi, bi <= bj.
__device__ __forceinline__ void decode_tile(int t, int& bi, int& bj)
{
    int b = (int)((sqrtf(8.0f * (float)t + 1.0f) - 1.0f) * 0.5f);
    while ((b + 1) * (b + 2) / 2 <= t) ++b;
    while (b * (b + 1) / 2 > t)       --b;
    bj = b;
    bi = t - b * (b + 1) / 2;
}

__device__ __forceinline__ unsigned int pack_bf16_2(float a, float b)
{
    __hip_bfloat16 ha = __float2bfloat16(a), hb = __float2bfloat16(b);
    unsigned short ua, ub;
    __builtin_memcpy(&ua, &ha, 2); __builtin_memcpy(&ub, &hb, 2);
    return (unsigned int)ua | ((unsigned int)ub << 16);
}

// ---------------- normalize: one wave per row ----------------
__global__ __launch_bounds__(256)
void normalize_k(const float* __restrict__ z, __hip_bfloat16* __restrict__ zn)
{
    const int lane = threadIdx.x & 63, wave = threadIdx.x >> 6;
    const int row  = blockIdx.x * 4 + wave;
    const float4* zr = (const float4*)(z + (size_t)row * DIM);
    const float4 a = zr[lane];
    const float4 b = zr[lane + 64];
    float ss = a.x*a.x + a.y*a.y + a.z*a.z + a.w*a.w
             + b.x*b.x + b.y*b.y + b.z*b.z + b.w*b.w;
    #pragma unroll
    for (int off = 1; off < 64; off <<= 1) ss += __shfl_xor(ss, off);
    const float inv = 1.0f / fmaxf(sqrtf(ss), 1e-12f);
    uint2* zo = (uint2*)(zn + (size_t)row * DIM);
    uint2 o0, o1;
    o0.x = pack_bf16_2(a.x * inv, a.y * inv);
    o0.y = pack_bf16_2(a.z * inv, a.w * inv);
    o1.x = pack_bf16_2(b.x * inv, b.y * inv);
    o1.y = pack_bf16_2(b.z * inv, b.w * inv);
    zo[lane]      = o0;
    zo[lane + 64] = o1;
}

// ---------------- sim pass: 128x128 upper-tri tiles, BK=32, 16 KB single-buffer ----------------
// LDS layout: 8 segs/side of 1KB in exact MFMA A-frag order:
// seg s (rows s*16..s*16+15), slot l = (row s*16+(l&15), k (l>>4)*8).
// Fragment read = seg_base + lane*16B -> conflict-free, matches global_load_lds pattern.
template<int PASS, bool STORE>
__global__ __launch_bounds__(256, 4)
void sim_pass(const __hip_bfloat16* __restrict__ zn,
              const int*   __restrict__ labels,
              const float* __restrict__ mu_d,
              const float* __restrict__ inv2s2,
              float*  __restrict__ rowsum,
              float*  __restrict__ rowsumsq,
              double* __restrict__ neg_acc,
              __half* __restrict__ simout)
{
    __shared__ unsigned short Asm[4096];   // 8 KB
    __shared__ unsigned short Bsm[4096];   // 8 KB
    __shared__ float redbuf[4];

    const int tid  = threadIdx.x;
    const int wave = tid >> 6;
    const int lane = tid & 63;
    const int f_l  = lane & 15;
    const int q_l  = lane >> 4;

    int bi, bj;
    decode_tile(blockIdx.x, bi, bj);
    const int R0 = bi * 128, C0 = bj * 128;
    const int wr = wave >> 1, wc = wave & 1;

    auto issue = [&](int k0) {
        #pragma unroll
        for (int q = 0; q < 2; ++q) {
            const int s  = wave * 2 + q;               // seg 0..7
            const int gk = k0 + q_l * 8;
            const __hip_bfloat16* ga = zn + (size_t)(R0 + s * 16 + f_l) * DIM + gk;
            const __hip_bfloat16* gb = zn + (size_t)(C0 + s * 16 + f_l) * DIM + gk;
            __builtin_amdgcn_global_load_lds(
                (const __attribute__((address_space(1))) unsigned int*)ga,
                (__attribute__((address_space(3))) unsigned int*)(Asm + s * 512 + lane * 8),
                16, 0, 0);
            __builtin_amdgcn_global_load_lds(
                (const __attribute__((address_space(1))) unsigned int*)gb,
                (__attribute__((address_space(3))) unsigned int*)(Bsm + s * 512 + lane * 8),
                16, 0, 0);
        }
    };

    f32x4 acc[4][4];
    #pragma unroll
    for (int r = 0; r < 4; ++r)
        #pragma unroll
        for (int c = 0; c < 4; ++c)
            acc[r][c] = (f32x4){0.f, 0.f, 0.f, 0.f};

    issue(0);

    for (int ki = 0; ki < 16; ++ki) {
        __syncthreads();                  // loads(ki) landed in LDS
        bf16x8 af[4], bfr[4];
        #pragma unroll
        for (int r = 0; r < 4; ++r)
            af[r] = *(const bf16x8*)(Asm + (wr * 4 + r) * 512 + lane * 8);
        #pragma unroll
        for (int c = 0; c < 4; ++c)
            bfr[c] = *(const bf16x8*)(Bsm + (wc * 4 + c) * 512 + lane * 8);
        __syncthreads();                  // all reads done -> buffer free
        if (ki < 15) issue((ki + 1) * 32);   // in flight during MFMA below
        #pragma unroll
        for (int r = 0; r < 4; ++r)
            #pragma unroll
            for (int c = 0; c < 4; ++c)
                acc[r][c] = __builtin_amdgcn_mfma_f32_16x16x32_bf16(af[r], bfr[c], acc[r][c], 0, 0, 0);
    }
    __syncthreads();                      // before reusing Asm as scratch

    // C/D layout: col = f_l, row = q_l*4 + u
    if (STORE) {
        __half* base = simout + (size_t)blockIdx.x * 16384 + wave * 4096;
        #pragma unroll
        for (int r = 0; r < 4; ++r)
            #pragma unroll
            for (int c = 0; c < 4; ++c) {
                const f32x4 v = acc[r][c];
                unsigned long long p =
                      (unsigned long long)__half_as_ushort(__float2half(v[0]))
                    | ((unsigned long long)__half_as_ushort(__float2half(v[1])) << 16)
                    | ((unsigned long long)__half_as_ushort(__float2half(v[2])) << 32)
                    | ((unsigned long long)__half_as_ushort(__float2half(v[3])) << 48);
                __builtin_nontemporal_store(p,
                    (unsigned long long*)(base + (r * 4 + c) * 256 + lane * 4));
            }
    }

    if (PASS == 0) {
        float* cs = (float*)Asm;          // col sums (C-side), 128
        float* cq = cs + 128;
        float* rs = cs + 256;             // row sums (mirror, R-side)
        float* rq = cs + 384;
        cs[tid] = 0.f; cs[tid + 256] = 0.f;
        __syncthreads();
        #pragma unroll
        for (int c = 0; c < 4; ++c) {
            float s = 0.f, sq = 0.f;
            #pragma unroll
            for (int r = 0; r < 4; ++r) {
                const f32x4 v = acc[r][c];
                #pragma unroll
                for (int u = 0; u < 4; ++u) { s += v[u]; sq += v[u] * v[u]; }
            }
            atomicAdd(&cs[wc * 64 + c * 16 + f_l], s);
            atomicAdd(&cq[wc * 64 + c * 16 + f_l], sq);
        }
        if (bi != bj) {
            #pragma unroll
            for (int r = 0; r < 4; ++r) {
                float s0 = 0, s1 = 0, s2 = 0, s3 = 0, q0 = 0, q1 = 0, q2 = 0, q3 = 0;
                #pragma unroll
                for (int c = 0; c < 4; ++c) {
                    const f32x4 v = acc[r][c];
                    s0 += v[0]; s1 += v[1]; s2 += v[2]; s3 += v[3];
                    q0 += v[0] * v[0]; q1 += v[1] * v[1]; q2 += v[2] * v[2]; q3 += v[3] * v[3];
                }
                #pragma unroll
                for (int off = 1; off < 16; off <<= 1) {
                    s0 += __shfl_xor(s0, off); s1 += __shfl_xor(s1, off);
                    s2 += __shfl_xor(s2, off); s3 += __shfl_xor(s3, off);
                    q0 += __shfl_xor(q0, off); q1 += __shfl_xor(q1, off);
                    q2 += __shfl_xor(q2, off); q3 += __shfl_xor(q3, off);
                }
                if (f_l == 0) {
                    const int base = wr * 64 + r * 16 + q_l * 4;
                    atomicAdd(&rs[base + 0], s0); atomicAdd(&rs[base + 1], s1);
                    atomicAdd(&rs[base + 2], s2); atomicAdd(&rs[base + 3], s3);
                    atomicAdd(&rq[base + 0], q0); atomicAdd(&rq[base + 1], q1);
                    atomicAdd(&rq[base + 2], q2); atomicAdd(&rq[base + 3], q3);
                }
            }
        }
        __syncthreads();
        if (tid < 128) {
            atomicAdd(&rowsum[C0 + tid],   cs[tid]);
            atomicAdd(&rowsumsq[C0 + tid], cq[tid]);
            if (bi != bj) {
                atomicAdd(&rowsum[R0 + tid],   rs[tid]);
                atomicAdd(&rowsumsq[R0 + tid], rq[tid]);
            }
        }
    } else {
        // recompute fallback (ws too small for simout)
        int labj[4]; float muj[4], isj[4];
        #pragma unroll
        for (int c = 0; c < 4; ++c) {
            const int j = C0 + wc * 64 + c * 16 + f_l;
            labj[c] = labels[j]; muj[c] = mu_d[j]; isj[c] = inv2s2[j];
        }
        float local = 0.f;
        #pragma unroll
        for (int r = 0; r < 4; ++r) {
            const int ib = R0 + wr * 64 + r * 16 + q_l * 4;
            #pragma unroll
            for (int u = 0; u < 4; ++u) {
                const int   li = labels[ib + u];
                const float mi = mu_d[ib + u];
                const float vi = inv2s2[ib + u];
                #pragma unroll
                for (int c = 0; c < 4; ++c) {
                    const float s  = acc[r][c][u];
                    const float dj = (1.0f - s) - muj[c];
                    float e = __expf(s * TEMP_INV + dj * dj * isj[c]);
                    if (bi != bj) {
                        const float di = (1.0f - s) - mi;
                        e += __expf(s * TEMP_INV + di * di * vi);
                    }
                    local += (li != labj[c]) ? e : 0.f;
                }
            }
        }
        #pragma unroll
        for (int off = 1; off < 64; off <<= 1) local += __shfl_xor(local, off);
        if (lane == 0) redbuf[wave] = local;
        __syncthreads();
        if (tid == 0)
            atomicAdd(neg_acc, (double)(redbuf[0] + redbuf[1] + redbuf[2] + redbuf[3]));
    }
}

// ---------------- streaming neg-sum from stored sim (stats fused) ----------------
__global__ __launch_bounds__(256)
void neg_stream_k(const __half* __restrict__ sim,
                  const int*   __restrict__ labels,
                  const float* __restrict__ rowsum,
                  const float* __restrict__ rowsumsq,
                  double* __restrict__ neg_acc)
{
    __shared__ int   labI[128], labJ[128];
    __shared__ float muI[128], muJ[128], isI[128], isJ[128];
    __shared__ float redbuf[4];
    const int tid = threadIdx.x;
    int bi, bj;
    decode_tile(blockIdx.x, bi, bj);
    const int R0 = bi * 128, C0 = bj * 128;
    {
        const int base = (tid < 128) ? R0 : C0;
        const int j = base + (tid & 127);
        const float s  = rowsum[j];
        const float sq = rowsumsq[j];
        const float mean_sim = s * (1.0f / NTOT);
        const float var = (sq - s * mean_sim) * (1.0f / (NTOT - 1));
        const float mu = 1.0f - mean_sim;
        const float is = 1.0f / (2.0f * var);
        const int   lb = labels[j];
        if (tid < 128) { labI[tid] = lb; muI[tid] = mu; isI[tid] = is; }
        else { labJ[tid - 128] = lb; muJ[tid - 128] = mu; isJ[tid - 128] = is; }
    }
    __syncthreads();
    const bool diag = (bi == bj);
    const unsigned long long* base =
        (const unsigned long long*)(sim + (size_t)blockIdx.x * 16384);
    float local = 0.f;
    #pragma unroll 4
    for (int it = 0; it < 16; ++it) {
        const int qd = it * 256 + tid;         // quad index 0..4095
        const unsigned long long v = __builtin_nontemporal_load(base + qd);
        const int wv = qd >> 10, rc = (qd >> 6) & 15, ln = qd & 63;
        const int wr = wv >> 1, wc = wv & 1, r = rc >> 2, c = rc & 3;
        const int f = ln & 15, q = ln >> 4;
        const int irow = wr * 64 + r * 16 + q * 4;
        const int jcol = wc * 64 + c * 16 + f;
        const int   lj = labJ[jcol];
        const float mj = muJ[jcol], sj = isJ[jcol];
        #pragma unroll
        for (int u = 0; u < 4; ++u) {
            const float s = __half2float(__ushort_as_half((unsigned short)(v >> (16 * u))));
            if (labI[irow + u] != lj) {
                const float d  = 1.0f - s;
                const float dj = d - mj;
                float e = __expf(s * TEMP_INV + dj * dj * sj);
                if (!diag) {
                    const float di = d - muI[irow + u];
                    e += __expf(s * TEMP_INV + di * di * isI[irow + u]);
                }
                local += e;
            }
        }
    }
    #pragma unroll
    for (int off = 1; off < 64; off <<= 1) local += __shfl_xor(local, off);
    if ((tid & 63) == 0) redbuf[tid >> 6] = local;
    __syncthreads();
    if (tid == 0)
        atomicAdd(neg_acc, (double)(redbuf[0] + redbuf[1] + redbuf[2] + redbuf[3]));
}

// ---------------- stats finalize (fallback path only) ----------------
__global__ void finalize_stats_k(const float* __restrict__ rowsum,
                                 const float* __restrict__ rowsumsq,
                                 float* __restrict__ mu_d,
                                 float* __restrict__ inv2s2)
{
    const int j = blockIdx.x * blockDim.x + threadIdx.x;
    if (j < NTOT) {
        const float s  = rowsum[j];
        const float sq = rowsumsq[j];
        const float mean_sim = s * (1.0f / NTOT);
        const float var = (sq - s * mean_sim) * (1.0f / (NTOT - 1));
        mu_d[j]   = 1.0f - mean_sim;
        inv2s2[j] = 1.0f / (2.0f * var);
    }
}

// ---------------- positive pairs ----------------
__global__ __launch_bounds__(256)
void pos_k(const __hip_bfloat16* __restrict__ zn, const int* __restrict__ labels,
           double* __restrict__ pos_acc)
{
    const int wave = threadIdx.x >> 6, lane = threadIdx.x & 63;
    const int pair = blockIdx.x * 4 + wave;
    const __hip_bfloat16* a = zn + (size_t)pair * DIM;
    const __hip_bfloat16* b = zn + (size_t)(pair + BATCH) * DIM;
    float s = 0.f;
    for (int k = lane; k < DIM; k += 64)
        s += __bfloat162float(a[k]) * __bfloat162float(b[k]);
    #pragma unroll
    for (int off = 32; off > 0; off >>= 1) s += __shfl_down(s, off);
    if (lane == 0 && labels[pair] == labels[pair + BATCH])
        atomicAdd(pos_acc, (double)__expf(s * TEMP_INV));
}

// ---------------- final loss ----------------
__global__ void loss_k(const double* __restrict__ accs, float* __restrict__ out)
{
    const double neg = accs[0], pos = accs[1];
    out[0] = (float)(-log(pos / (pos + neg)));
}

extern "C" void kernel_launch(void* const* d_in, const int* in_sizes, int n_in,
                              void* d_out, int out_size, void* d_ws, size_t ws_size,
                              hipStream_t stream)
{
    const float* z      = (const float*)d_in[0];
    const int*   labels = (const int*)d_in[1];
    float* out = (float*)d_out;

    char* ws = (char*)d_ws;
    __hip_bfloat16* zn = (__hip_bfloat16*)ws;
    const size_t ZN_BYTES = (size_t)NTOT * DIM * 2;        // 8 MiB
    float*  rowsum   = (float*)(ws + ZN_BYTES);
    float*  rowsumsq = rowsum + NTOT;
    float*  mu_d     = rowsum + 2 * NTOT;
    float*  inv2s2   = rowsum + 3 * NTOT;
    double* accs     = (double*)(rowsum + 4 * NTOT);       // [0]=neg, [1]=pos
    const size_t simoff = (ZN_BYTES + 4 * NTOT * sizeof(float) + 2 * sizeof(double) + 255) & ~(size_t)255;
    __half* simbuf = (__half*)(ws + simoff);
    const bool store = ws_size >= simoff + SIM_ELEMS * sizeof(__half);

    hipMemsetAsync(rowsum, 0, 4 * NTOT * sizeof(float) + 2 * sizeof(double), stream);

    normalize_k<<<NTOT / 4, 256, 0, stream>>>(z, zn);

    if (store) {
        sim_pass<0, true><<<NBLK, 256, 0, stream>>>(zn, labels, mu_d, inv2s2,
                                                    rowsum, rowsumsq, accs, simbuf);
        neg_stream_k<<<NBLK, 256, 0, stream>>>(simbuf, labels, rowsum, rowsumsq, accs);
    } else {
        sim_pass<0, false><<<NBLK, 256, 0, stream>>>(zn, labels, mu_d, inv2s2,
                                                     rowsum, rowsumsq, accs, nullptr);
        finalize_stats_k<<<NTOT / 256, 256, 0, stream>>>(rowsum, rowsumsq, mu_d, inv2s2);
        sim_pass<1, false><<<NBLK, 256, 0, stream>>>(zn, labels, mu_d, inv2s2,
                                                     rowsum, rowsumsq, accs, nullptr);
    }
    pos_k<<<BATCH / 4, 256, 0, stream>>>(zn, labels, accs + 1);
    loss_k<<<1, 1, 0, stream>>>(accs, out);
}